// Round 3
// baseline (4664.954 us; speedup 1.0000x reference)
//
#include <hip/hip_runtime.h>
#include <math.h>

#define Lc 2048
#define Bc 64
#define Hc 1024

// One wave per (l,b) row: computes the dot-score, stores it to ws, bumps a
// per-b counter. The wave that completes row count for b (returns Lc-1) then
// computes ha = hidden[b]^T @ Am, adds the affect term, and does the softmax
// for that b — overlapped with the remaining streaming waves.
__global__ __launch_bounds__(256) void fused_attn_kernel(
        const float* __restrict__ hidden,
        const float* __restrict__ enc,
        const float* __restrict__ emb,
        const float* __restrict__ am,
        float* __restrict__ out,
        int* __restrict__ cnt,
        float* __restrict__ energies) {
    int wid  = threadIdx.x >> 6;
    int lane = threadIdx.x & 63;
    int r = blockIdx.x * 4 + wid;      // r = l*B + b, [0, L*B)
    int b = r & (Bc - 1);
    int l = r >> 6;

    // ---- streaming phase (identical structure to R0) ----
    const float4* __restrict__ erow = (const float4*)(enc + (size_t)r * Hc);
    const float4* __restrict__ hrow = (const float4*)(hidden + (size_t)b * Hc);
    float acc = 0.f;
#pragma unroll
    for (int i = 0; i < 4; ++i) {          // 4 * 64 lanes * 4 floats = 1024 = H
        float4 e = erow[i * 64 + lane];
        float4 h = hrow[i * 64 + lane];
        acc += e.x * h.x + e.y * h.y + e.z * h.z + e.w * h.w;
    }
    for (int off = 1; off < 64; off <<= 1) acc += __shfl_xor(acc, off);

    int old = 0;
    if (lane == 0) {
        __hip_atomic_store(&energies[(size_t)b * Lc + l], acc,
                           __ATOMIC_RELAXED, __HIP_MEMORY_SCOPE_AGENT);
        old = __hip_atomic_fetch_add(&cnt[b], 1,
                                     __ATOMIC_ACQ_REL, __HIP_MEMORY_SCOPE_AGENT);
    }
    old = __shfl(old, 0);
    if (old != Lc - 1) return;

    // ---- finisher wave for this b ----
    // ha[k] = sum_h hidden[b,h] * am[h,k]   (k = 0..2)
    float s0 = 0.f, s1 = 0.f, s2 = 0.f;
    for (int h = lane; h < Hc; h += 64) {
        float hv = hidden[b * Hc + h];
        s0 += hv * am[h * 3 + 0];
        s1 += hv * am[h * 3 + 1];
        s2 += hv * am[h * 3 + 2];
    }
    for (int off = 1; off < 64; off <<= 1) {
        s0 += __shfl_xor(s0, off);
        s1 += __shfl_xor(s1, off);
        s2 += __shfl_xor(s2, off);
    }

    // gather energies (agent-scope loads: written by waves on other XCDs),
    // add affect term, softmax over L
    float vals[32];
    float m = -INFINITY;
#pragma unroll
    for (int i = 0; i < 32; ++i) {         // 32 * 64 = 2048 = L
        int ll = lane + i * 64;
        float e = __hip_atomic_load(&energies[(size_t)b * Lc + ll],
                                    __ATOMIC_RELAXED, __HIP_MEMORY_SCOPE_AGENT);
        const float* em = emb + ((size_t)ll * Bc + b) * 3;
        e += s0 * em[0] + s1 * em[1] + s2 * em[2];
        vals[i] = e;
        m = fmaxf(m, e);
    }
    for (int off = 1; off < 64; off <<= 1) m = fmaxf(m, __shfl_xor(m, off));

    float s = 0.f;
#pragma unroll
    for (int i = 0; i < 32; ++i) {
        vals[i] = __expf(vals[i] - m);
        s += vals[i];
    }
    for (int off = 1; off < 64; off <<= 1) s += __shfl_xor(s, off);
    float inv = 1.0f / s;

#pragma unroll
    for (int i = 0; i < 32; ++i)
        out[(size_t)b * Lc + lane + i * 64] = vals[i] * inv;
}

extern "C" void kernel_launch(void* const* d_in, const int* in_sizes, int n_in,
                              void* d_out, int out_size, void* d_ws, size_t ws_size,
                              hipStream_t stream) {
    const float* hidden = (const float*)d_in[0];   // [1,B,H]
    const float* enc    = (const float*)d_in[1];   // [L,B,H]
    const float* emb    = (const float*)d_in[2];   // [L,B,A]
    const float* am     = (const float*)d_in[3];   // [H,A]
    float* out = (float*)d_out;                    // [B,1,L]

    int*   cnt      = (int*)d_ws;                       // B counters
    float* energies = (float*)((char*)d_ws + 1024);     // B*L floats

    hipMemsetAsync(cnt, 0, Bc * sizeof(int), stream);   // deterministic per call
    fused_attn_kernel<<<(Lc * Bc) / 4, 256, 0, stream>>>(
        hidden, enc, emb, am, out, cnt, energies);
}

// Round 4
// 94.373 us; speedup vs baseline: 49.4310x; 49.4310x over previous
//
#include <hip/hip_runtime.h>
#include <math.h>

#define Lc 2048
#define Bc 64
#define Hc 1024

// ---------------- kernel 1: pure streaming dot ------------------------------------
// One wave per row r = l*B + b (enc row is contiguous H floats).
// energies[b,l] = hidden[b,:] . enc[l,b,:]
__global__ __launch_bounds__(256) void energy_kernel(const float* __restrict__ hidden,
                                                     const float* __restrict__ enc,
                                                     float* __restrict__ energies) {
    int wid  = threadIdx.x >> 6;
    int lane = threadIdx.x & 63;
    int r = blockIdx.x * 4 + wid;       // r in [0, L*B)
    int b = r & (Bc - 1);               // B = 64
    int l = r >> 6;                     // r / B

    const float4* __restrict__ erow = (const float4*)(enc + (size_t)r * Hc);
    const float4* __restrict__ hrow = (const float4*)(hidden + (size_t)b * Hc);

    float acc = 0.f;
#pragma unroll
    for (int i = 0; i < 4; ++i) {        // 4 * 64 lanes * 4 floats = 1024 = H
        float4 e = erow[i * 64 + lane];
        float4 h = hrow[i * 64 + lane];
        acc += e.x * h.x + e.y * h.y + e.z * h.z + e.w * h.w;
    }
    for (int off = 1; off < 64; off <<= 1) acc += __shfl_xor(acc, off);

    if (lane == 0) energies[(size_t)b * Lc + l] = acc;
}

// ---------------- kernel 2: ha + affect + row softmax ------------------------------
// One block per b. Phase 1: ha[k] = sum_h hidden[b,h]*am[h,k]. Phase 2: add
// affect term to energies row, softmax over L, write out [B,1,L].
__global__ __launch_bounds__(256) void softmax_kernel(const float* __restrict__ hidden,
                                                      const float* __restrict__ emb,
                                                      const float* __restrict__ am,
                                                      const float* __restrict__ energies,
                                                      float* __restrict__ out) {
    int b = blockIdx.x;
    int t = threadIdx.x;
    int wave = t >> 6;

    // ---- phase 1: ha (block reduce) ----
    float s0 = 0.f, s1 = 0.f, s2 = 0.f;
#pragma unroll
    for (int i = 0; i < 4; ++i) {        // 4 * 256 = 1024 = H
        int h = t + i * 256;
        float hv = hidden[b * Hc + h];
        s0 += hv * am[h * 3 + 0];
        s1 += hv * am[h * 3 + 1];
        s2 += hv * am[h * 3 + 2];
    }
    for (int off = 1; off < 64; off <<= 1) {
        s0 += __shfl_xor(s0, off);
        s1 += __shfl_xor(s1, off);
        s2 += __shfl_xor(s2, off);
    }
    __shared__ float red[3][4];
    if ((t & 63) == 0) { red[0][wave] = s0; red[1][wave] = s1; red[2][wave] = s2; }
    __syncthreads();
    float ha0 = red[0][0] + red[0][1] + red[0][2] + red[0][3];
    float ha1 = red[1][0] + red[1][1] + red[1][2] + red[1][3];
    float ha2 = red[2][0] + red[2][1] + red[2][2] + red[2][3];
    __syncthreads();

    // ---- phase 2: affect + softmax ----
    const float* row = energies + (size_t)b * Lc;
    float vals[8];
    float m = -INFINITY;
#pragma unroll
    for (int i = 0; i < 8; ++i) {        // 8 * 256 = 2048 = L
        int ll = t + i * 256;
        const float* em = emb + ((size_t)ll * Bc + b) * 3;
        float e = row[ll] + ha0 * em[0] + ha1 * em[1] + ha2 * em[2];
        vals[i] = e;
        m = fmaxf(m, e);
    }
    __shared__ float sred[4];
    for (int off = 1; off < 64; off <<= 1) m = fmaxf(m, __shfl_xor(m, off));
    if ((t & 63) == 0) sred[wave] = m;
    __syncthreads();
    m = fmaxf(fmaxf(sred[0], sred[1]), fmaxf(sred[2], sred[3]));
    __syncthreads();

    float s = 0.f;
#pragma unroll
    for (int i = 0; i < 8; ++i) {
        vals[i] = __expf(vals[i] - m);
        s += vals[i];
    }
    for (int off = 1; off < 64; off <<= 1) s += __shfl_xor(s, off);
    if ((t & 63) == 0) sred[wave] = s;
    __syncthreads();
    s = sred[0] + sred[1] + sred[2] + sred[3];
    float inv = 1.0f / s;

#pragma unroll
    for (int i = 0; i < 8; ++i) out[(size_t)b * Lc + t + i * 256] = vals[i] * inv;
}

extern "C" void kernel_launch(void* const* d_in, const int* in_sizes, int n_in,
                              void* d_out, int out_size, void* d_ws, size_t ws_size,
                              hipStream_t stream) {
    const float* hidden = (const float*)d_in[0];   // [1,B,H]
    const float* enc    = (const float*)d_in[1];   // [L,B,H]
    const float* emb    = (const float*)d_in[2];   // [L,B,A]
    const float* am     = (const float*)d_in[3];   // [H,A]
    float* out = (float*)d_out;                    // [B,1,L]

    float* energies = (float*)d_ws;                // B*L floats

    energy_kernel<<<(Lc * Bc) / 4, 256, 0, stream>>>(hidden, enc, energies);
    softmax_kernel<<<Bc, 256, 0, stream>>>(hidden, emb, am, energies, out);
}